// Round 15
// baseline (487.160 us; speedup 1.0000x reference)
//
#include <hip/hip_runtime.h>
#include <math.h>

#define HH 4
#define CC 32
#define HC 128

__device__ __forceinline__ float relu4x(float v) { return fmaxf(v, 0.f); }

// =================== node projection: customer_x[101] -> user_x[32] ===================
__global__ __launch_bounds__(256) void k_proj101(
    const float* __restrict__ X, const float* __restrict__ W,
    const float* __restrict__ b, float* __restrict__ Y, int N) {
  __shared__ float xs[64][105];
  __shared__ float Ws[101 * 32];
  __shared__ float bs[32];
  for (int i = threadIdx.x; i < 101 * 32; i += 256) Ws[i] = W[i];
  if (threadIdx.x < 32) bs[threadIdx.x] = b[threadIdx.x];
  int row0 = blockIdx.x * 64;
  for (int idx = threadIdx.x; idx < 64 * 25; idx += 256) {
    int f = idx % 25, r = idx / 25;
    int row = row0 + r;
    float4 v = make_float4(0.f, 0.f, 0.f, 0.f);
    if (row < N) v = *(const float4*)(X + (size_t)row * 101 + f * 4);
    xs[r][f * 4 + 0] = v.x; xs[r][f * 4 + 1] = v.y;
    xs[r][f * 4 + 2] = v.z; xs[r][f * 4 + 3] = v.w;
  }
  if (threadIdx.x < 64) {
    int row = row0 + threadIdx.x;
    xs[threadIdx.x][100] = (row < N) ? X[(size_t)row * 101 + 100] : 0.f;
  }
  __syncthreads();
  int q = threadIdx.x & 3;
  int r = threadIdx.x >> 2;
  float acc[8];
#pragma unroll
  for (int j = 0; j < 8; ++j) acc[j] = bs[q * 8 + j];
  for (int k = 0; k < 101; ++k) {
    float xv = xs[r][k];
    float4 w0 = *(const float4*)&Ws[k * 32 + q * 8];
    float4 w1 = *(const float4*)&Ws[k * 32 + q * 8 + 4];
    acc[0] += xv * w0.x; acc[1] += xv * w0.y; acc[2] += xv * w0.z; acc[3] += xv * w0.w;
    acc[4] += xv * w1.x; acc[5] += xv * w1.y; acc[6] += xv * w1.z; acc[7] += xv * w1.w;
  }
  int row = row0 + r;
  if (row < N) {
    float* yr = Y + (size_t)row * 32 + q * 8;
    *(float4*)yr = make_float4(acc[0], acc[1], acc[2], acc[3]);
    *(float4*)(yr + 4) = make_float4(acc[4], acc[5], acc[6], acc[7]);
  }
}

__global__ __launch_bounds__(256) void k_item_proj(
    const float* __restrict__ X, const float* __restrict__ W,
    const float* __restrict__ b, float* __restrict__ Y, int N) {
  int t = blockIdx.x * 256 + threadIdx.x;
  if (t >= N * 32) return;
  int i = t >> 5, c = t & 31;
  Y[t] = X[i] * W[c] + b[c];
}

// =================== K-chunked tiled GEMM (R10-proven, unchanged) ===================
template <int K, int INRELU, int OUTRELU>
__global__ __launch_bounds__(256, 3) void k_tile(
    const float* __restrict__ X, const float* __restrict__ inb,
    const float* __restrict__ W, const float* __restrict__ b,
    float* __restrict__ Y, int N) {
  constexpr int KB = 32;
  constexpr int NCH = K / KB;
  __shared__ float xsT[KB][132];
  __shared__ float ws[KB][128];
  __shared__ float bsl[128];
  __shared__ float inbs[K];
  for (int i = threadIdx.x; i < 128; i += 256) bsl[i] = b[i];
  for (int i = threadIdx.x; i < K; i += 256) inbs[i] = inb ? inb[i] : 0.f;
  __syncthreads();
  int row0 = blockIdx.x * 128;
  int tx = threadIdx.x & 15, ty = threadIdx.x >> 4;
  float acc[8][8];
#pragma unroll
  for (int j = 0; j < 8; ++j) {
    float bj = bsl[tx * 8 + j];
#pragma unroll
    for (int i = 0; i < 8; ++i) acc[i][j] = bj;
  }
  for (int ch = 0; ch < NCH; ++ch) {
    int k0 = ch * KB;
    for (int idx = threadIdx.x; idx < 128 * 8; idx += 256) {
      int f = idx & 7, r = idx >> 3;
      int row = row0 + r;
      float4 v = make_float4(0.f, 0.f, 0.f, 0.f);
      if (row < N) {
        v = *(const float4*)(X + (size_t)row * K + k0 + f * 4);
        v.x += inbs[k0 + f * 4 + 0]; v.y += inbs[k0 + f * 4 + 1];
        v.z += inbs[k0 + f * 4 + 2]; v.w += inbs[k0 + f * 4 + 3];
        if (INRELU) { v.x = relu4x(v.x); v.y = relu4x(v.y); v.z = relu4x(v.z); v.w = relu4x(v.w); }
      }
      xsT[f * 4 + 0][r] = v.x; xsT[f * 4 + 1][r] = v.y;
      xsT[f * 4 + 2][r] = v.z; xsT[f * 4 + 3][r] = v.w;
    }
    for (int idx = threadIdx.x; idx < KB * 32; idx += 256) {
      int c4 = (idx & 31) * 4, kk = idx >> 5;
      *(float4*)&ws[kk][c4] = *(const float4*)(W + (size_t)(k0 + kk) * 128 + c4);
    }
    __syncthreads();
#pragma unroll 2
    for (int k = 0; k < KB; ++k) {
      float4 a0 = *(const float4*)&xsT[k][ty * 8];
      float4 a1 = *(const float4*)&xsT[k][ty * 8 + 4];
      float4 b0 = *(const float4*)&ws[k][tx * 8];
      float4 b1 = *(const float4*)&ws[k][tx * 8 + 4];
      float av[8] = {a0.x, a0.y, a0.z, a0.w, a1.x, a1.y, a1.z, a1.w};
      float bv[8] = {b0.x, b0.y, b0.z, b0.w, b1.x, b1.y, b1.z, b1.w};
#pragma unroll
      for (int i = 0; i < 8; ++i)
#pragma unroll
        for (int j = 0; j < 8; ++j) acc[i][j] += av[i] * bv[j];
    }
    __syncthreads();
  }
#pragma unroll
  for (int i = 0; i < 8; ++i) {
    int row = row0 + ty * 8 + i;
    if (row < N) {
      float o[8];
#pragma unroll
      for (int j = 0; j < 8; ++j) o[j] = OUTRELU ? fmaxf(acc[i][j], 0.f) : acc[i][j];
      float* yr = Y + (size_t)row * 128 + tx * 8;
      *(float4*)yr = make_float4(o[0], o[1], o[2], o[3]);
      *(float4*)(yr + 4) = make_float4(o[4], o[5], o[6], o[7]);
    }
  }
}

// =================== dual K=32 GEMM (R10-proven, unchanged) ===================
__global__ __launch_bounds__(256, 3) void k_dual32(
    const float* __restrict__ X,
    const float* __restrict__ W1, const float* __restrict__ b1,
    const float* __restrict__ W2, const float* __restrict__ b2,
    float* __restrict__ Y1, float* __restrict__ Y2, int N) {
  __shared__ float xsT[32][132];
  __shared__ float ws1[32][128];
  __shared__ float ws2[32][128];
  __shared__ float bsa[128];
  __shared__ float bsb[128];
  for (int i = threadIdx.x; i < 128; i += 256) { bsa[i] = b1[i]; bsb[i] = b2[i]; }
  int row0 = blockIdx.x * 128;
  for (int idx = threadIdx.x; idx < 128 * 8; idx += 256) {
    int f = idx & 7, r = idx >> 3;
    int row = row0 + r;
    float4 v = make_float4(0.f, 0.f, 0.f, 0.f);
    if (row < N) v = *(const float4*)(X + (size_t)row * 32 + f * 4);
    xsT[f * 4 + 0][r] = v.x; xsT[f * 4 + 1][r] = v.y;
    xsT[f * 4 + 2][r] = v.z; xsT[f * 4 + 3][r] = v.w;
  }
  for (int idx = threadIdx.x; idx < 32 * 32; idx += 256) {
    int c4 = (idx & 31) * 4, kk = idx >> 5;
    *(float4*)&ws1[kk][c4] = *(const float4*)(W1 + (size_t)kk * 128 + c4);
    *(float4*)&ws2[kk][c4] = *(const float4*)(W2 + (size_t)kk * 128 + c4);
  }
  __syncthreads();
  int tx = threadIdx.x & 15, ty = threadIdx.x >> 4;
  float acc1[8][8], acc2[8][8];
#pragma unroll
  for (int j = 0; j < 8; ++j) {
    float c1 = bsa[tx * 8 + j], c2 = bsb[tx * 8 + j];
#pragma unroll
    for (int i = 0; i < 8; ++i) { acc1[i][j] = c1; acc2[i][j] = c2; }
  }
#pragma unroll 2
  for (int k = 0; k < 32; ++k) {
    float4 a0 = *(const float4*)&xsT[k][ty * 8];
    float4 a1 = *(const float4*)&xsT[k][ty * 8 + 4];
    float4 p0 = *(const float4*)&ws1[k][tx * 8];
    float4 p1 = *(const float4*)&ws1[k][tx * 8 + 4];
    float4 q0 = *(const float4*)&ws2[k][tx * 8];
    float4 q1 = *(const float4*)&ws2[k][tx * 8 + 4];
    float av[8] = {a0.x, a0.y, a0.z, a0.w, a1.x, a1.y, a1.z, a1.w};
    float pv[8] = {p0.x, p0.y, p0.z, p0.w, p1.x, p1.y, p1.z, p1.w};
    float qv[8] = {q0.x, q0.y, q0.z, q0.w, q1.x, q1.y, q1.z, q1.w};
#pragma unroll
    for (int i = 0; i < 8; ++i)
#pragma unroll
      for (int j = 0; j < 8; ++j) { acc1[i][j] += av[i] * pv[j]; acc2[i][j] += av[i] * qv[j]; }
  }
#pragma unroll
  for (int i = 0; i < 8; ++i) {
    int row = row0 + ty * 8 + i;
    if (row < N) {
      float* y1 = Y1 + (size_t)row * 128 + tx * 8;
      float* y2 = Y2 + (size_t)row * 128 + tx * 8;
      *(float4*)y1 = make_float4(acc1[i][0], acc1[i][1], acc1[i][2], acc1[i][3]);
      *(float4*)(y1 + 4) = make_float4(acc1[i][4], acc1[i][5], acc1[i][6], acc1[i][7]);
      *(float4*)y2 = make_float4(acc2[i][0], acc2[i][1], acc2[i][2], acc2[i][3]);
      *(float4*)(y2 + 4) = make_float4(acc2[i][4], acc2[i][5], acc2[i][6], acc2[i][7]);
    }
  }
}

// =================== fully fused head: + X-prefetch double-buffer (T14) ===================
// Each thread's 4 staging coords (f,r) are FIXED; X chunk ch+1 loaded into named
// regs during chunk ch's compute. W1/Wc1 staging unchanged. Phase C unchanged.
__global__ __launch_bounds__(256, 3) void k_head_fused(
    const float* __restrict__ X, const float* __restrict__ inb,
    const float* __restrict__ W1, const float* __restrict__ b1,
    const float* __restrict__ W2, const float* __restrict__ b2,
    const float* __restrict__ Wc1, const float* __restrict__ bc1,
    const float* __restrict__ Wc2, const float* __restrict__ bc2,
    float* __restrict__ Z, float* __restrict__ S, int N) {
  __shared__ float xsT[32][132];
  __shared__ float ws[32][128];
  __shared__ float ws2[32][64];
  __shared__ float bsl[128];
  __shared__ float inbs[128];
  __shared__ float bsc[64];
  __shared__ float wc2s[64];
  for (int i = threadIdx.x; i < 128; i += 256) { bsl[i] = b1[i]; inbs[i] = inb[i]; }
  if (threadIdx.x < 64) { bsc[threadIdx.x] = bc1[threadIdx.x]; wc2s[threadIdx.x] = Wc2[threadIdx.x]; }
  __syncthreads();
  int row0 = blockIdx.x * 128;
  int tx = threadIdx.x & 15, ty = threadIdx.x >> 4;
  int ty8 = ty * 8;
  // fixed staging coordinates for this thread (q = 0..3)
  const int f0 = threadIdx.x & 7,         r0 = threadIdx.x >> 3;
  const int f1 = (threadIdx.x + 256) & 7, r1 = (threadIdx.x + 256) >> 3;
  const int f2 = (threadIdx.x + 512) & 7, r2 = (threadIdx.x + 512) >> 3;
  const int f3 = (threadIdx.x + 768) & 7, r3 = (threadIdx.x + 768) >> 3;
  const bool in0 = row0 + r0 < N, in1 = row0 + r1 < N, in2 = row0 + r2 < N, in3 = row0 + r3 < N;
  const float* xp0 = X + (size_t)(row0 + r0) * 128 + f0 * 4;
  const float* xp1 = X + (size_t)(row0 + r1) * 128 + f1 * 4;
  const float* xp2 = X + (size_t)(row0 + r2) * 128 + f2 * 4;
  const float* xp3 = X + (size_t)(row0 + r3) * 128 + f3 * 4;
  const float4 Z4 = make_float4(0.f, 0.f, 0.f, 0.f);
  float4 px0 = in0 ? *(const float4*)(xp0) : Z4;
  float4 px1 = in1 ? *(const float4*)(xp1) : Z4;
  float4 px2 = in2 ? *(const float4*)(xp2) : Z4;
  float4 px3 = in3 ? *(const float4*)(xp3) : Z4;

  float acc[8][8], accc[8][4];
#pragma unroll
  for (int j = 0; j < 4; ++j) {
    float b0 = bsl[tx * 4 + j], b1v = bsl[64 + tx * 4 + j], bc = bsc[tx * 4 + j];
#pragma unroll
    for (int i = 0; i < 8; ++i) { acc[i][j] = b0; acc[i][4 + j] = b1v; accc[i][j] = bc; }
  }
  // -------- main loop: X double-buffered through registers --------
  for (int ch = 0; ch < 4; ++ch) {
    int k0 = ch * 32;
    // write prefetched X (+inbs) to swizzled xsT
    {
      float4 v;
      int rx;
      v = px0;
      v.x += inbs[k0 + f0 * 4 + 0]; v.y += inbs[k0 + f0 * 4 + 1];
      v.z += inbs[k0 + f0 * 4 + 2]; v.w += inbs[k0 + f0 * 4 + 3];
      rx = r0 ^ ((f0 & 3) << 3);
      xsT[f0 * 4 + 0][rx] = v.x; xsT[f0 * 4 + 1][rx] = v.y;
      xsT[f0 * 4 + 2][rx] = v.z; xsT[f0 * 4 + 3][rx] = v.w;
      v = px1;
      v.x += inbs[k0 + f1 * 4 + 0]; v.y += inbs[k0 + f1 * 4 + 1];
      v.z += inbs[k0 + f1 * 4 + 2]; v.w += inbs[k0 + f1 * 4 + 3];
      rx = r1 ^ ((f1 & 3) << 3);
      xsT[f1 * 4 + 0][rx] = v.x; xsT[f1 * 4 + 1][rx] = v.y;
      xsT[f1 * 4 + 2][rx] = v.z; xsT[f1 * 4 + 3][rx] = v.w;
      v = px2;
      v.x += inbs[k0 + f2 * 4 + 0]; v.y += inbs[k0 + f2 * 4 + 1];
      v.z += inbs[k0 + f2 * 4 + 2]; v.w += inbs[k0 + f2 * 4 + 3];
      rx = r2 ^ ((f2 & 3) << 3);
      xsT[f2 * 4 + 0][rx] = v.x; xsT[f2 * 4 + 1][rx] = v.y;
      xsT[f2 * 4 + 2][rx] = v.z; xsT[f2 * 4 + 3][rx] = v.w;
      v = px3;
      v.x += inbs[k0 + f3 * 4 + 0]; v.y += inbs[k0 + f3 * 4 + 1];
      v.z += inbs[k0 + f3 * 4 + 2]; v.w += inbs[k0 + f3 * 4 + 3];
      rx = r3 ^ ((f3 & 3) << 3);
      xsT[f3 * 4 + 0][rx] = v.x; xsT[f3 * 4 + 1][rx] = v.y;
      xsT[f3 * 4 + 2][rx] = v.z; xsT[f3 * 4 + 3][rx] = v.w;
    }
    for (int idx = threadIdx.x; idx < 32 * 32; idx += 256) {
      int c4 = (idx & 31) * 4, kk = idx >> 5;
      *(float4*)&ws[kk][c4] = *(const float4*)(W1 + (size_t)(k0 + kk) * 128 + c4);
    }
    for (int idx = threadIdx.x; idx < 32 * 16; idx += 256) {
      int c4 = (idx & 15) * 4, kk = idx >> 4;
      *(float4*)&ws2[kk][c4] = *(const float4*)(Wc1 + (size_t)(k0 + kk) * 64 + c4);
    }
    __syncthreads();
    // issue next chunk's X loads; latency hides under the 32 k-step compute
    if (ch < 3) {
      int kn = k0 + 32;
      px0 = in0 ? *(const float4*)(xp0 + kn) : Z4;
      px1 = in1 ? *(const float4*)(xp1 + kn) : Z4;
      px2 = in2 ? *(const float4*)(xp2 + kn) : Z4;
      px3 = in3 ? *(const float4*)(xp3 + kn) : Z4;
    }
#pragma unroll 2
    for (int k = 0; k < 32; ++k) {
      int g8 = ((k >> 2) & 3) << 3;
      float4 a0 = *(const float4*)&xsT[k][ty8 ^ g8];
      float4 a1 = *(const float4*)&xsT[k][(ty8 ^ g8) + 4];
      float4 b0 = *(const float4*)&ws[k][tx * 4];
      float4 b1v = *(const float4*)&ws[k][64 + tx * 4];
      float4 cv = *(const float4*)&ws2[k][tx * 4];
      float av[8] = {a0.x, a0.y, a0.z, a0.w, a1.x, a1.y, a1.z, a1.w};
      float bv[8] = {b0.x, b0.y, b0.z, b0.w, b1v.x, b1v.y, b1v.z, b1v.w};
#pragma unroll
      for (int i = 0; i < 8; ++i) {
#pragma unroll
        for (int j = 0; j < 8; ++j) acc[i][j] += av[i] * bv[j];
        accc[i][0] += av[i] * cv.x; accc[i][1] += av[i] * cv.y;
        accc[i][2] += av[i] * cv.z; accc[i][3] += av[i] * cv.w;
      }
    }
    __syncthreads();
  }
  // -------- cls epilogue --------
  {
    float w2a = wc2s[tx * 4], w2b = wc2s[tx * 4 + 1], w2c = wc2s[tx * 4 + 2], w2d = wc2s[tx * 4 + 3];
    float bb2 = bc2[0];
#pragma unroll
    for (int i = 0; i < 8; ++i) {
      float p = fmaxf(accc[i][0], 0.f) * w2a + fmaxf(accc[i][1], 0.f) * w2b +
                fmaxf(accc[i][2], 0.f) * w2c + fmaxf(accc[i][3], 0.f) * w2d;
      p += __shfl_xor(p, 1, 16);
      p += __shfl_xor(p, 2, 16);
      p += __shfl_xor(p, 4, 16);
      p += __shfl_xor(p, 8, 16);
      int row = row0 + ty8 + i;
      if (row < N && tx == 0) S[row] = 1.f / (1.f + __expf(-(p + bb2)));
    }
  }
  // -------- phase C: out_z = relu(z1)@W2 + b2 (z1 never hits global) --------
  float acc3[8][8];
#pragma unroll
  for (int j = 0; j < 4; ++j) {
    float p0 = b2[tx * 4 + j], p1 = b2[64 + tx * 4 + j];
#pragma unroll
    for (int i = 0; i < 8; ++i) { acc3[i][j] = p0; acc3[i][4 + j] = p1; }
  }
  for (int ch = 0; ch < 4; ++ch) {
    if ((tx >> 2) == ch) {
      int txl = tx & 3;
#pragma unroll
      for (int j = 0; j < 4; ++j) {
        int lk = txl * 4 + j;
        int base = ty8 ^ (((lk >> 2) & 3) << 3);
        *(float4*)&xsT[lk][base] =
            make_float4(fmaxf(acc[0][j], 0.f), fmaxf(acc[1][j], 0.f),
                        fmaxf(acc[2][j], 0.f), fmaxf(acc[3][j], 0.f));
        *(float4*)&xsT[lk][base + 4] =
            make_float4(fmaxf(acc[4][j], 0.f), fmaxf(acc[5][j], 0.f),
                        fmaxf(acc[6][j], 0.f), fmaxf(acc[7][j], 0.f));
        int lk2 = 16 + txl * 4 + j;
        int base2 = ty8 ^ (((lk2 >> 2) & 3) << 3);
        *(float4*)&xsT[lk2][base2] =
            make_float4(fmaxf(acc[0][4 + j], 0.f), fmaxf(acc[1][4 + j], 0.f),
                        fmaxf(acc[2][4 + j], 0.f), fmaxf(acc[3][4 + j], 0.f));
        *(float4*)&xsT[lk2][base2 + 4] =
            make_float4(fmaxf(acc[4][4 + j], 0.f), fmaxf(acc[5][4 + j], 0.f),
                        fmaxf(acc[6][4 + j], 0.f), fmaxf(acc[7][4 + j], 0.f));
      }
    }
    for (int idx = threadIdx.x; idx < 32 * 32; idx += 256) {
      int c4 = (idx & 31) * 4, kk = idx >> 5;
      int gk = (kk < 16) ? (ch * 16 + kk) : (48 + ch * 16 + kk);
      *(float4*)&ws[kk][c4] = *(const float4*)(W2 + (size_t)gk * 128 + c4);
    }
    __syncthreads();
#pragma unroll 2
    for (int k = 0; k < 32; ++k) {
      int g8 = ((k >> 2) & 3) << 3;
      float4 a0 = *(const float4*)&xsT[k][ty8 ^ g8];
      float4 a1 = *(const float4*)&xsT[k][(ty8 ^ g8) + 4];
      float4 b0 = *(const float4*)&ws[k][tx * 4];
      float4 b1v = *(const float4*)&ws[k][64 + tx * 4];
      float av[8] = {a0.x, a0.y, a0.z, a0.w, a1.x, a1.y, a1.z, a1.w};
      float bv[8] = {b0.x, b0.y, b0.z, b0.w, b1v.x, b1v.y, b1v.z, b1v.w};
#pragma unroll
      for (int i = 0; i < 8; ++i)
#pragma unroll
        for (int j = 0; j < 8; ++j) acc3[i][j] += av[i] * bv[j];
    }
    __syncthreads();
  }
#pragma unroll
  for (int i = 0; i < 8; ++i) {
    int row = row0 + ty8 + i;
    if (row < N) {
      float* zr = Z + (size_t)row * 128;
      *(float4*)(zr + tx * 4) = make_float4(acc3[i][0], acc3[i][1], acc3[i][2], acc3[i][3]);
      *(float4*)(zr + 64 + tx * 4) = make_float4(acc3[i][4], acc3[i][5], acc3[i][6], acc3[i][7]);
    }
  }
}

// =================== CSR build (fused both directions) ===================

__global__ __launch_bounds__(256) void k_hist2(
    const int* __restrict__ src, const int* __restrict__ dst,
    int* __restrict__ histD, int* __restrict__ histS, int E) {
  int e = blockIdx.x * 256 + threadIdx.x;
  if (e >= E) return;
  atomicAdd(&histD[dst[e]], 1);
  atomicAdd(&histS[src[e]], 1);
}

#define SCAN_T 256
#define SCAN_V 4
#define SCAN_BLK 1024

__global__ __launch_bounds__(SCAN_T) void k_scan_local(
    const int* __restrict__ hist, int* __restrict__ starts,
    int* __restrict__ partials, int N) {
  __shared__ int sums[SCAN_T];
  int base = blockIdx.x * SCAN_BLK + threadIdx.x * SCAN_V;
  int v[SCAN_V];
  int s = 0;
#pragma unroll
  for (int i = 0; i < SCAN_V; ++i) { v[i] = (base + i < N) ? hist[base + i] : 0; s += v[i]; }
  sums[threadIdx.x] = s;
  __syncthreads();
  for (int off = 1; off < SCAN_T; off <<= 1) {
    int x = (threadIdx.x >= off) ? sums[threadIdx.x - off] : 0;
    __syncthreads();
    sums[threadIdx.x] += x;
    __syncthreads();
  }
  int run = (threadIdx.x > 0) ? sums[threadIdx.x - 1] : 0;
#pragma unroll
  for (int i = 0; i < SCAN_V; ++i) {
    if (base + i < N) starts[base + i] = run;
    run += v[i];
  }
  if (threadIdx.x == SCAN_T - 1) partials[blockIdx.x] = sums[SCAN_T - 1];
}

__global__ __launch_bounds__(SCAN_T) void k_scan_partials(int* partials, int nb) {
  __shared__ int s[SCAN_T];
  s[threadIdx.x] = (threadIdx.x < nb) ? partials[threadIdx.x] : 0;
  __syncthreads();
  for (int off = 1; off < SCAN_T; off <<= 1) {
    int x = (threadIdx.x >= off) ? s[threadIdx.x - off] : 0;
    __syncthreads();
    s[threadIdx.x] += x;
    __syncthreads();
  }
  if (threadIdx.x < nb) partials[threadIdx.x] = (threadIdx.x > 0) ? s[threadIdx.x - 1] : 0;
}

__global__ __launch_bounds__(256) void k_scan_add(
    int* __restrict__ starts, const int* __restrict__ partials,
    int* __restrict__ cursor, int N) {
  int i = blockIdx.x * 256 + threadIdx.x;
  if (i >= N) return;
  int v = starts[i] + partials[i / SCAN_BLK];
  starts[i] = v;
  cursor[i] = v;
}

__global__ __launch_bounds__(256) void k_scatter2(
    const int* __restrict__ src, const int* __restrict__ dst,
    int* __restrict__ cur1, int* __restrict__ cur2,
    int2* __restrict__ ebuf1, int2* __restrict__ ebuf2, int E) {
  int e = blockIdx.x * 256 + threadIdx.x;
  if (e >= E) return;
  int s = src[e], d = dst[e];
  int p1 = atomicAdd(&cur1[d], 1);
  ebuf1[p1] = make_int2(s, e);
  int p2 = atomicAdd(&cur2[s], 1);
  ebuf2[p2] = make_int2(d, e);
}

// =================== fused GATv2 edge phase: 4-way ILP online softmax (R14-proven) ===================
template <int USE_EF>
__global__ __launch_bounds__(256) void k_gat(
    const float* __restrict__ xl, const float* __restrict__ xr,
    const int2* __restrict__ ebuf, const int* __restrict__ starts,
    const int* __restrict__ counts, const float* __restrict__ att,
    const float* __restrict__ eattr, const float* __restrict__ We,
    float* __restrict__ agg, int N) {
  int wid = (blockIdx.x * 256 + threadIdx.x) >> 6;
  if (wid >= N) return;
  int lane = threadIdx.x & 63;
  int g = lane >> 4;
  int t = lane & 15;
  int c = g * 32 + t * 2;
  float att0 = att[c], att1 = att[c + 1];
  float2 we0, we1, we2;
  if (USE_EF) {
    we0 = *(const float2*)(We + 0 * HC + c);
    we1 = *(const float2*)(We + 1 * HC + c);
    we2 = *(const float2*)(We + 2 * HC + c);
  }
  float2 xrv = *(const float2*)(xr + (size_t)wid * HC + c);
  int st = starts[wid], cnt = counts[wid];
  const float NEGINF = -3.402823466e38f;
  float m0 = NEGINF, d0 = 0.f, a00 = 0.f, a01 = 0.f;
  float m1 = NEGINF, d1 = 0.f, a10 = 0.f, a11 = 0.f;
  float m2 = NEGINF, d2 = 0.f, a20 = 0.f, a21 = 0.f;
  float m3 = NEGINF, d3 = 0.f, a30 = 0.f, a31 = 0.f;
  int i = 0;
  for (; i + 3 < cnt; i += 4) {
    int2 seA = ebuf[st + i];
    int2 seB = ebuf[st + i + 1];
    int2 seC = ebuf[st + i + 2];
    int2 seD = ebuf[st + i + 3];
    float2 xlA = *(const float2*)(xl + (size_t)seA.x * HC + c);
    float2 xlB = *(const float2*)(xl + (size_t)seB.x * HC + c);
    float2 xlC = *(const float2*)(xl + (size_t)seC.x * HC + c);
    float2 xlD = *(const float2*)(xl + (size_t)seD.x * HC + c);
    float xA0 = xlA.x + xrv.x, xA1 = xlA.y + xrv.y;
    float xB0 = xlB.x + xrv.x, xB1 = xlB.y + xrv.y;
    float xC0 = xlC.x + xrv.x, xC1 = xlC.y + xrv.y;
    float xD0 = xlD.x + xrv.x, xD1 = xlD.y + xrv.y;
    if (USE_EF) {
      const float* eaA = eattr + (size_t)seA.y * 3;
      const float* eaB = eattr + (size_t)seB.y * 3;
      const float* eaC = eattr + (size_t)seC.y * 3;
      const float* eaD = eattr + (size_t)seD.y * 3;
      float eA0 = eaA[0], eA1 = eaA[1], eA2 = eaA[2];
      float eB0 = eaB[0], eB1 = eaB[1], eB2 = eaB[2];
      float eC0 = eaC[0], eC1 = eaC[1], eC2 = eaC[2];
      float eD0 = eaD[0], eD1 = eaD[1], eD2 = eaD[2];
      xA0 += eA0 * we0.x + eA1 * we1.x + eA2 * we2.x;
      xA1 += eA0 * we0.y + eA1 * we1.y + eA2 * we2.y;
      xB0 += eB0 * we0.x + eB1 * we1.x + eB2 * we2.x;
      xB1 += eB0 * we0.y + eB1 * we1.y + eB2 * we2.y;
      xC0 += eC0 * we0.x + eC1 * we1.x + eC2 * we2.x;
      xC1 += eC0 * we0.y + eC1 * we1.y + eC2 * we2.y;
      xD0 += eD0 * we0.x + eD1 * we1.x + eD2 * we2.x;
      xD1 += eD0 * we0.y + eD1 * we1.y + eD2 * we2.y;
    }
    xA0 = (xA0 > 0.f) ? xA0 : 0.2f * xA0;
    xA1 = (xA1 > 0.f) ? xA1 : 0.2f * xA1;
    xB0 = (xB0 > 0.f) ? xB0 : 0.2f * xB0;
    xB1 = (xB1 > 0.f) ? xB1 : 0.2f * xB1;
    xC0 = (xC0 > 0.f) ? xC0 : 0.2f * xC0;
    xC1 = (xC1 > 0.f) ? xC1 : 0.2f * xC1;
    xD0 = (xD0 > 0.f) ? xD0 : 0.2f * xD0;
    xD1 = (xD1 > 0.f) ? xD1 : 0.2f * xD1;
    float pA = xA0 * att0 + xA1 * att1;
    float pB = xB0 * att0 + xB1 * att1;
    float pC = xC0 * att0 + xC1 * att1;
    float pD = xD0 * att0 + xD1 * att1;
    pA += __shfl_xor(pA, 1, 16);
    pB += __shfl_xor(pB, 1, 16);
    pC += __shfl_xor(pC, 1, 16);
    pD += __shfl_xor(pD, 1, 16);
    pA += __shfl_xor(pA, 2, 16);
    pB += __shfl_xor(pB, 2, 16);
    pC += __shfl_xor(pC, 2, 16);
    pD += __shfl_xor(pD, 2, 16);
    pA += __shfl_xor(pA, 4, 16);
    pB += __shfl_xor(pB, 4, 16);
    pC += __shfl_xor(pC, 4, 16);
    pD += __shfl_xor(pD, 4, 16);
    pA += __shfl_xor(pA, 8, 16);
    pB += __shfl_xor(pB, 8, 16);
    pC += __shfl_xor(pC, 8, 16);
    pD += __shfl_xor(pD, 8, 16);
    float nmA = fmaxf(m0, pA), nmB = fmaxf(m1, pB);
    float nmC = fmaxf(m2, pC), nmD = fmaxf(m3, pD);
    float sA = __expf(m0 - nmA), wA = __expf(pA - nmA);
    float sB = __expf(m1 - nmB), wB = __expf(pB - nmB);
    float sC = __expf(m2 - nmC), wC = __expf(pC - nmC);
    float sD = __expf(m3 - nmD), wD = __expf(pD - nmD);
    d0 = d0 * sA + wA; a00 = a00 * sA + wA * xlA.x; a01 = a01 * sA + wA * xlA.y; m0 = nmA;
    d1 = d1 * sB + wB; a10 = a10 * sB + wB * xlB.x; a11 = a11 * sB + wB * xlB.y; m1 = nmB;
    d2 = d2 * sC + wC; a20 = a20 * sC + wC * xlC.x; a21 = a21 * sC + wC * xlC.y; m2 = nmC;
    d3 = d3 * sD + wD; a30 = a30 * sD + wD * xlD.x; a31 = a31 * sD + wD * xlD.y; m3 = nmD;
  }
  for (; i < cnt; ++i) {
    int2 se = ebuf[st + i];
    float2 xlv = *(const float2*)(xl + (size_t)se.x * HC + c);
    float x0 = xlv.x + xrv.x, x1 = xlv.y + xrv.y;
    if (USE_EF) {
      const float* ea = eattr + (size_t)se.y * 3;
      float e0 = ea[0], e1 = ea[1], e2 = ea[2];
      x0 += e0 * we0.x + e1 * we1.x + e2 * we2.x;
      x1 += e0 * we0.y + e1 * we1.y + e2 * we2.y;
    }
    x0 = (x0 > 0.f) ? x0 : 0.2f * x0;
    x1 = (x1 > 0.f) ? x1 : 0.2f * x1;
    float p = x0 * att0 + x1 * att1;
    p += __shfl_xor(p, 1, 16);
    p += __shfl_xor(p, 2, 16);
    p += __shfl_xor(p, 4, 16);
    p += __shfl_xor(p, 8, 16);
    float nm = fmaxf(m0, p);
    float s = __expf(m0 - nm), w = __expf(p - nm);
    d0 = d0 * s + w; a00 = a00 * s + w * xlv.x; a01 = a01 * s + w * xlv.y; m0 = nm;
  }
  float M = fmaxf(fmaxf(m0, m1), fmaxf(m2, m3));
  float s0 = (m0 > NEGINF) ? __expf(m0 - M) : 0.f;
  float s1 = (m1 > NEGINF) ? __expf(m1 - M) : 0.f;
  float s2 = (m2 > NEGINF) ? __expf(m2 - M) : 0.f;
  float s3 = (m3 > NEGINF) ? __expf(m3 - M) : 0.f;
  float dsum = d0 * s0 + d1 * s1 + d2 * s2 + d3 * s3;
  float a0 = a00 * s0 + a10 * s1 + a20 * s2 + a30 * s3;
  float a1 = a01 * s0 + a11 * s1 + a21 * s2 + a31 * s3;
  float inv = (dsum > 0.f) ? 1.f / dsum : 0.f;
  *(float2*)(agg + (size_t)wid * HC + c) = make_float2(a0 * inv, a1 * inv);
}

static inline int imin(int a, int b) { return a < b ? a : b; }

extern "C" void kernel_launch(void* const* d_in, const int* in_sizes, int n_in,
                              void* d_out, int out_size, void* d_ws, size_t ws_size,
                              hipStream_t stream) {
  const float* customer_x = (const float*)d_in[0];
  const float* fund_x     = (const float*)d_in[1];
  const int*   edge_src   = (const int*)d_in[2];
  const int*   edge_dst   = (const int*)d_in[3];
  const float* edge_attr  = (const float*)d_in[4];
  const float* user_W = (const float*)d_in[5];
  const float* user_b = (const float*)d_in[6];
  const float* item_W = (const float*)d_in[7];
  const float* item_b = (const float*)d_in[8];
  const float* c1_Wl = (const float*)d_in[9];
  const float* c1_bl = (const float*)d_in[10];
  const float* c1_Wr = (const float*)d_in[11];
  const float* c1_br = (const float*)d_in[12];
  const float* c1_att = (const float*)d_in[13];
  const float* c1_We  = (const float*)d_in[14];
  const float* c1_bias = (const float*)d_in[15];
  const float* c2_Wl = (const float*)d_in[16];
  const float* c2_bl = (const float*)d_in[17];
  const float* c2_Wr = (const float*)d_in[18];
  const float* c2_br = (const float*)d_in[19];
  const float* c2_att = (const float*)d_in[20];
  const float* c2_bias = (const float*)d_in[21];
  const float* proj_W1 = (const float*)d_in[22];
  const float* proj_b1 = (const float*)d_in[23];
  const float* proj_W2 = (const float*)d_in[24];
  const float* proj_b2 = (const float*)d_in[25];
  const float* cls_W1 = (const float*)d_in[26];
  const float* cls_b1 = (const float*)d_in[27];
  const float* cls_W2 = (const float*)d_in[28];
  const float* cls_b2 = (const float*)d_in[29];

  const int Ncust = in_sizes[0] / 101;
  const int Nitem = in_sizes[1];
  const int E     = in_sizes[2];

  // -------- workspace layout (~141 MiB) --------
  float* w = (float*)d_ws;
  float* user_x  = w; w += (size_t)Ncust * 32;
  float* item_x0 = w; w += (size_t)Nitem * 32;
  float* bufC    = w; w += (size_t)Ncust * HC;   // xl1 -> (conv2 xl2 in first Nitem rows)
  float* bufD    = w; w += (size_t)Nitem * HC;   // xr1 -> agg1 (in-place)
  float* bufE    = w; w += (size_t)Ncust * HC;   // xr2 -> agg2 (in-place)
  int* hist1   = (int*)w; w += Nitem;
  int* hist2   = (int*)w; w += Ncust;
  int* starts1 = (int*)w; w += Nitem;
  int* cursor1 = (int*)w; w += Nitem;
  int* starts2 = (int*)w; w += Ncust;
  int* cursor2 = (int*)w; w += Ncust;
  int* partials = (int*)w; w += 512;
  int2* ebuf1 = (int2*)w; w += (size_t)E * 2;
  int2* ebuf2 = (int2*)w; w += (size_t)E * 2;
  if ((size_t)((char*)w - (char*)d_ws) > ws_size) return;

  float* out_scores = (float*)d_out;
  float* out_z      = out_scores + Ncust;

  const int egrid = (E + 255) / 256;
  const int nb1 = (Nitem + SCAN_BLK - 1) / SCAN_BLK;
  const int nb2 = (Ncust + SCAN_BLK - 1) / SCAN_BLK;
  const int nt1 = (Ncust + 127) / 128;
  const int nt2 = (Nitem + 127) / 128;

  // -------- CSR build (fused passes) --------
  hipMemsetAsync(hist1, 0, (size_t)(Nitem + Ncust) * 4, stream);
  k_hist2<<<egrid, 256, 0, stream>>>(edge_src, edge_dst, hist1, hist2, E);
  k_scan_local<<<nb1, SCAN_T, 0, stream>>>(hist1, starts1, partials, Nitem);
  k_scan_partials<<<1, SCAN_T, 0, stream>>>(partials, nb1);
  k_scan_add<<<(Nitem + 255) / 256, 256, 0, stream>>>(starts1, partials, cursor1, Nitem);
  k_scan_local<<<nb2, SCAN_T, 0, stream>>>(hist2, starts2, partials, Ncust);
  k_scan_partials<<<1, SCAN_T, 0, stream>>>(partials, nb2);
  k_scan_add<<<(Ncust + 255) / 256, 256, 0, stream>>>(starts2, partials, cursor2, Ncust);
  k_scatter2<<<egrid, 256, 0, stream>>>(edge_src, edge_dst, cursor1, cursor2, ebuf1, ebuf2, E);

  // -------- node projections --------
  k_proj101<<<(Ncust + 63) / 64, 256, 0, stream>>>(customer_x, user_W, user_b, user_x, Ncust);
  k_item_proj<<<(Nitem * 32 + 255) / 256, 256, 0, stream>>>(fund_x, item_W, item_b, item_x0, Nitem);

  // -------- conv linear parts from user_x (xl1 + xr2 in one pass) --------
  k_dual32<<<nt1, 256, 0, stream>>>(user_x, c1_Wl, c1_bl, c2_Wr, c2_br, bufC, bufE, Ncust);
  k_tile<32, 0, 0><<<nt2, 256, 0, stream>>>(item_x0, nullptr, c1_Wr, c1_br, bufD, Nitem);

  // -------- conv1 edge phase (customer -> fund), agg1 in-place into bufD --------
  k_gat<1><<<(Nitem + 3) / 4, 256, 0, stream>>>(bufC, bufD, ebuf1, starts1, hist1,
                                                c1_att, edge_attr, c1_We, bufD, Nitem);

  // -------- conv2: xl2 then edge phase (fund -> customer) in-place bufE --------
  k_tile<128, 1, 0><<<nt2, 256, 0, stream>>>(bufD, c1_bias, c2_Wl, c2_bl, bufC, Nitem);
  k_gat<0><<<(Ncust + 3) / 4, 256, 0, stream>>>(bufC, bufE, ebuf2, starts2, hist2,
                                                c2_att, nullptr, nullptr, bufE, Ncust);

  // -------- fused head: proj1 + cls + proj2 --------
  k_head_fused<<<nt1, 256, 0, stream>>>(bufE, c2_bias, proj_W1, proj_b1, proj_W2, proj_b2,
                                        cls_W1, cls_b1, cls_W2, cls_b2,
                                        out_z, out_scores, Ncust);
}

// Round 16
// 478.671 us; speedup vs baseline: 1.0177x; 1.0177x over previous
//
#include <hip/hip_runtime.h>
#include <math.h>

#define HH 4
#define CC 32
#define HC 128

__device__ __forceinline__ float relu4x(float v) { return fmaxf(v, 0.f); }

// =================== node projection: customer_x[101] -> user_x[32] ===================
__global__ __launch_bounds__(256) void k_proj101(
    const float* __restrict__ X, const float* __restrict__ W,
    const float* __restrict__ b, float* __restrict__ Y, int N) {
  __shared__ float xs[64][105];
  __shared__ float Ws[101 * 32];
  __shared__ float bs[32];
  for (int i = threadIdx.x; i < 101 * 32; i += 256) Ws[i] = W[i];
  if (threadIdx.x < 32) bs[threadIdx.x] = b[threadIdx.x];
  int row0 = blockIdx.x * 64;
  for (int idx = threadIdx.x; idx < 64 * 25; idx += 256) {
    int f = idx % 25, r = idx / 25;
    int row = row0 + r;
    float4 v = make_float4(0.f, 0.f, 0.f, 0.f);
    if (row < N) v = *(const float4*)(X + (size_t)row * 101 + f * 4);
    xs[r][f * 4 + 0] = v.x; xs[r][f * 4 + 1] = v.y;
    xs[r][f * 4 + 2] = v.z; xs[r][f * 4 + 3] = v.w;
  }
  if (threadIdx.x < 64) {
    int row = row0 + threadIdx.x;
    xs[threadIdx.x][100] = (row < N) ? X[(size_t)row * 101 + 100] : 0.f;
  }
  __syncthreads();
  int q = threadIdx.x & 3;
  int r = threadIdx.x >> 2;
  float acc[8];
#pragma unroll
  for (int j = 0; j < 8; ++j) acc[j] = bs[q * 8 + j];
  for (int k = 0; k < 101; ++k) {
    float xv = xs[r][k];
    float4 w0 = *(const float4*)&Ws[k * 32 + q * 8];
    float4 w1 = *(const float4*)&Ws[k * 32 + q * 8 + 4];
    acc[0] += xv * w0.x; acc[1] += xv * w0.y; acc[2] += xv * w0.z; acc[3] += xv * w0.w;
    acc[4] += xv * w1.x; acc[5] += xv * w1.y; acc[6] += xv * w1.z; acc[7] += xv * w1.w;
  }
  int row = row0 + r;
  if (row < N) {
    float* yr = Y + (size_t)row * 32 + q * 8;
    *(float4*)yr = make_float4(acc[0], acc[1], acc[2], acc[3]);
    *(float4*)(yr + 4) = make_float4(acc[4], acc[5], acc[6], acc[7]);
  }
}

__global__ __launch_bounds__(256) void k_item_proj(
    const float* __restrict__ X, const float* __restrict__ W,
    const float* __restrict__ b, float* __restrict__ Y, int N) {
  int t = blockIdx.x * 256 + threadIdx.x;
  if (t >= N * 32) return;
  int i = t >> 5, c = t & 31;
  Y[t] = X[i] * W[c] + b[c];
}

// =================== K-chunked tiled GEMM (R10-proven, unchanged) ===================
template <int K, int INRELU, int OUTRELU>
__global__ __launch_bounds__(256, 3) void k_tile(
    const float* __restrict__ X, const float* __restrict__ inb,
    const float* __restrict__ W, const float* __restrict__ b,
    float* __restrict__ Y, int N) {
  constexpr int KB = 32;
  constexpr int NCH = K / KB;
  __shared__ float xsT[KB][132];
  __shared__ float ws[KB][128];
  __shared__ float bsl[128];
  __shared__ float inbs[K];
  for (int i = threadIdx.x; i < 128; i += 256) bsl[i] = b[i];
  for (int i = threadIdx.x; i < K; i += 256) inbs[i] = inb ? inb[i] : 0.f;
  __syncthreads();
  int row0 = blockIdx.x * 128;
  int tx = threadIdx.x & 15, ty = threadIdx.x >> 4;
  float acc[8][8];
#pragma unroll
  for (int j = 0; j < 8; ++j) {
    float bj = bsl[tx * 8 + j];
#pragma unroll
    for (int i = 0; i < 8; ++i) acc[i][j] = bj;
  }
  for (int ch = 0; ch < NCH; ++ch) {
    int k0 = ch * KB;
    for (int idx = threadIdx.x; idx < 128 * 8; idx += 256) {
      int f = idx & 7, r = idx >> 3;
      int row = row0 + r;
      float4 v = make_float4(0.f, 0.f, 0.f, 0.f);
      if (row < N) {
        v = *(const float4*)(X + (size_t)row * K + k0 + f * 4);
        v.x += inbs[k0 + f * 4 + 0]; v.y += inbs[k0 + f * 4 + 1];
        v.z += inbs[k0 + f * 4 + 2]; v.w += inbs[k0 + f * 4 + 3];
        if (INRELU) { v.x = relu4x(v.x); v.y = relu4x(v.y); v.z = relu4x(v.z); v.w = relu4x(v.w); }
      }
      xsT[f * 4 + 0][r] = v.x; xsT[f * 4 + 1][r] = v.y;
      xsT[f * 4 + 2][r] = v.z; xsT[f * 4 + 3][r] = v.w;
    }
    for (int idx = threadIdx.x; idx < KB * 32; idx += 256) {
      int c4 = (idx & 31) * 4, kk = idx >> 5;
      *(float4*)&ws[kk][c4] = *(const float4*)(W + (size_t)(k0 + kk) * 128 + c4);
    }
    __syncthreads();
#pragma unroll 2
    for (int k = 0; k < KB; ++k) {
      float4 a0 = *(const float4*)&xsT[k][ty * 8];
      float4 a1 = *(const float4*)&xsT[k][ty * 8 + 4];
      float4 b0 = *(const float4*)&ws[k][tx * 8];
      float4 b1 = *(const float4*)&ws[k][tx * 8 + 4];
      float av[8] = {a0.x, a0.y, a0.z, a0.w, a1.x, a1.y, a1.z, a1.w};
      float bv[8] = {b0.x, b0.y, b0.z, b0.w, b1.x, b1.y, b1.z, b1.w};
#pragma unroll
      for (int i = 0; i < 8; ++i)
#pragma unroll
        for (int j = 0; j < 8; ++j) acc[i][j] += av[i] * bv[j];
    }
    __syncthreads();
  }
#pragma unroll
  for (int i = 0; i < 8; ++i) {
    int row = row0 + ty * 8 + i;
    if (row < N) {
      float o[8];
#pragma unroll
      for (int j = 0; j < 8; ++j) o[j] = OUTRELU ? fmaxf(acc[i][j], 0.f) : acc[i][j];
      float* yr = Y + (size_t)row * 128 + tx * 8;
      *(float4*)yr = make_float4(o[0], o[1], o[2], o[3]);
      *(float4*)(yr + 4) = make_float4(o[4], o[5], o[6], o[7]);
    }
  }
}

// =================== dual K=32 GEMM (R10-proven, unchanged) ===================
__global__ __launch_bounds__(256, 3) void k_dual32(
    const float* __restrict__ X,
    const float* __restrict__ W1, const float* __restrict__ b1,
    const float* __restrict__ W2, const float* __restrict__ b2,
    float* __restrict__ Y1, float* __restrict__ Y2, int N) {
  __shared__ float xsT[32][132];
  __shared__ float ws1[32][128];
  __shared__ float ws2[32][128];
  __shared__ float bsa[128];
  __shared__ float bsb[128];
  for (int i = threadIdx.x; i < 128; i += 256) { bsa[i] = b1[i]; bsb[i] = b2[i]; }
  int row0 = blockIdx.x * 128;
  for (int idx = threadIdx.x; idx < 128 * 8; idx += 256) {
    int f = idx & 7, r = idx >> 3;
    int row = row0 + r;
    float4 v = make_float4(0.f, 0.f, 0.f, 0.f);
    if (row < N) v = *(const float4*)(X + (size_t)row * 32 + f * 4);
    xsT[f * 4 + 0][r] = v.x; xsT[f * 4 + 1][r] = v.y;
    xsT[f * 4 + 2][r] = v.z; xsT[f * 4 + 3][r] = v.w;
  }
  for (int idx = threadIdx.x; idx < 32 * 32; idx += 256) {
    int c4 = (idx & 31) * 4, kk = idx >> 5;
    *(float4*)&ws1[kk][c4] = *(const float4*)(W1 + (size_t)kk * 128 + c4);
    *(float4*)&ws2[kk][c4] = *(const float4*)(W2 + (size_t)kk * 128 + c4);
  }
  __syncthreads();
  int tx = threadIdx.x & 15, ty = threadIdx.x >> 4;
  float acc1[8][8], acc2[8][8];
#pragma unroll
  for (int j = 0; j < 8; ++j) {
    float c1 = bsa[tx * 8 + j], c2 = bsb[tx * 8 + j];
#pragma unroll
    for (int i = 0; i < 8; ++i) { acc1[i][j] = c1; acc2[i][j] = c2; }
  }
#pragma unroll 2
  for (int k = 0; k < 32; ++k) {
    float4 a0 = *(const float4*)&xsT[k][ty * 8];
    float4 a1 = *(const float4*)&xsT[k][ty * 8 + 4];
    float4 p0 = *(const float4*)&ws1[k][tx * 8];
    float4 p1 = *(const float4*)&ws1[k][tx * 8 + 4];
    float4 q0 = *(const float4*)&ws2[k][tx * 8];
    float4 q1 = *(const float4*)&ws2[k][tx * 8 + 4];
    float av[8] = {a0.x, a0.y, a0.z, a0.w, a1.x, a1.y, a1.z, a1.w};
    float pv[8] = {p0.x, p0.y, p0.z, p0.w, p1.x, p1.y, p1.z, p1.w};
    float qv[8] = {q0.x, q0.y, q0.z, q0.w, q1.x, q1.y, q1.z, q1.w};
#pragma unroll
    for (int i = 0; i < 8; ++i)
#pragma unroll
      for (int j = 0; j < 8; ++j) { acc1[i][j] += av[i] * pv[j]; acc2[i][j] += av[i] * qv[j]; }
  }
#pragma unroll
  for (int i = 0; i < 8; ++i) {
    int row = row0 + ty * 8 + i;
    if (row < N) {
      float* y1 = Y1 + (size_t)row * 128 + tx * 8;
      float* y2 = Y2 + (size_t)row * 128 + tx * 8;
      *(float4*)y1 = make_float4(acc1[i][0], acc1[i][1], acc1[i][2], acc1[i][3]);
      *(float4*)(y1 + 4) = make_float4(acc1[i][4], acc1[i][5], acc1[i][6], acc1[i][7]);
      *(float4*)y2 = make_float4(acc2[i][0], acc2[i][1], acc2[i][2], acc2[i][3]);
      *(float4*)(y2 + 4) = make_float4(acc2[i][4], acc2[i][5], acc2[i][6], acc2[i][7]);
    }
  }
}

// =================== fully fused head (R11/R14-proven: swizzled xsT + split cols) ===================
__global__ __launch_bounds__(256, 3) void k_head_fused(
    const float* __restrict__ X, const float* __restrict__ inb,
    const float* __restrict__ W1, const float* __restrict__ b1,
    const float* __restrict__ W2, const float* __restrict__ b2,
    const float* __restrict__ Wc1, const float* __restrict__ bc1,
    const float* __restrict__ Wc2, const float* __restrict__ bc2,
    float* __restrict__ Z, float* __restrict__ S, int N) {
  __shared__ float xsT[32][132];
  __shared__ float ws[32][128];
  __shared__ float ws2[32][64];
  __shared__ float bsl[128];
  __shared__ float inbs[128];
  __shared__ float bsc[64];
  __shared__ float wc2s[64];
  for (int i = threadIdx.x; i < 128; i += 256) { bsl[i] = b1[i]; inbs[i] = inb[i]; }
  if (threadIdx.x < 64) { bsc[threadIdx.x] = bc1[threadIdx.x]; wc2s[threadIdx.x] = Wc2[threadIdx.x]; }
  __syncthreads();
  int row0 = blockIdx.x * 128;
  int tx = threadIdx.x & 15, ty = threadIdx.x >> 4;
  int ty8 = ty * 8;
  float acc[8][8], accc[8][4];
#pragma unroll
  for (int j = 0; j < 4; ++j) {
    float b0 = bsl[tx * 4 + j], b1v = bsl[64 + tx * 4 + j], bc = bsc[tx * 4 + j];
#pragma unroll
    for (int i = 0; i < 8; ++i) { acc[i][j] = b0; acc[i][4 + j] = b1v; accc[i][j] = bc; }
  }
  for (int ch = 0; ch < 4; ++ch) {
    int k0 = ch * 32;
    for (int idx = threadIdx.x; idx < 128 * 8; idx += 256) {
      int f = idx & 7, r = idx >> 3;
      int row = row0 + r;
      float4 v = make_float4(0.f, 0.f, 0.f, 0.f);
      if (row < N) {
        v = *(const float4*)(X + (size_t)row * 128 + k0 + f * 4);
        v.x += inbs[k0 + f * 4 + 0]; v.y += inbs[k0 + f * 4 + 1];
        v.z += inbs[k0 + f * 4 + 2]; v.w += inbs[k0 + f * 4 + 3];
      }
      int rx = r ^ ((f & 3) << 3);
      xsT[f * 4 + 0][rx] = v.x; xsT[f * 4 + 1][rx] = v.y;
      xsT[f * 4 + 2][rx] = v.z; xsT[f * 4 + 3][rx] = v.w;
    }
    for (int idx = threadIdx.x; idx < 32 * 32; idx += 256) {
      int c4 = (idx & 31) * 4, kk = idx >> 5;
      *(float4*)&ws[kk][c4] = *(const float4*)(W1 + (size_t)(k0 + kk) * 128 + c4);
    }
    for (int idx = threadIdx.x; idx < 32 * 16; idx += 256) {
      int c4 = (idx & 15) * 4, kk = idx >> 4;
      *(float4*)&ws2[kk][c4] = *(const float4*)(Wc1 + (size_t)(k0 + kk) * 64 + c4);
    }
    __syncthreads();
#pragma unroll 2
    for (int k = 0; k < 32; ++k) {
      int g8 = ((k >> 2) & 3) << 3;
      float4 a0 = *(const float4*)&xsT[k][ty8 ^ g8];
      float4 a1 = *(const float4*)&xsT[k][(ty8 ^ g8) + 4];
      float4 b0 = *(const float4*)&ws[k][tx * 4];
      float4 b1v = *(const float4*)&ws[k][64 + tx * 4];
      float4 cv = *(const float4*)&ws2[k][tx * 4];
      float av[8] = {a0.x, a0.y, a0.z, a0.w, a1.x, a1.y, a1.z, a1.w};
      float bv[8] = {b0.x, b0.y, b0.z, b0.w, b1v.x, b1v.y, b1v.z, b1v.w};
#pragma unroll
      for (int i = 0; i < 8; ++i) {
#pragma unroll
        for (int j = 0; j < 8; ++j) acc[i][j] += av[i] * bv[j];
        accc[i][0] += av[i] * cv.x; accc[i][1] += av[i] * cv.y;
        accc[i][2] += av[i] * cv.z; accc[i][3] += av[i] * cv.w;
      }
    }
    __syncthreads();
  }
  {
    float w2a = wc2s[tx * 4], w2b = wc2s[tx * 4 + 1], w2c = wc2s[tx * 4 + 2], w2d = wc2s[tx * 4 + 3];
    float bb2 = bc2[0];
#pragma unroll
    for (int i = 0; i < 8; ++i) {
      float p = fmaxf(accc[i][0], 0.f) * w2a + fmaxf(accc[i][1], 0.f) * w2b +
                fmaxf(accc[i][2], 0.f) * w2c + fmaxf(accc[i][3], 0.f) * w2d;
      p += __shfl_xor(p, 1, 16);
      p += __shfl_xor(p, 2, 16);
      p += __shfl_xor(p, 4, 16);
      p += __shfl_xor(p, 8, 16);
      int row = row0 + ty8 + i;
      if (row < N && tx == 0) S[row] = 1.f / (1.f + __expf(-(p + bb2)));
    }
  }
  float acc3[8][8];
#pragma unroll
  for (int j = 0; j < 4; ++j) {
    float p0 = b2[tx * 4 + j], p1 = b2[64 + tx * 4 + j];
#pragma unroll
    for (int i = 0; i < 8; ++i) { acc3[i][j] = p0; acc3[i][4 + j] = p1; }
  }
  for (int ch = 0; ch < 4; ++ch) {
    if ((tx >> 2) == ch) {
      int txl = tx & 3;
#pragma unroll
      for (int j = 0; j < 4; ++j) {
        int lk = txl * 4 + j;
        int base = ty8 ^ (((lk >> 2) & 3) << 3);
        *(float4*)&xsT[lk][base] =
            make_float4(fmaxf(acc[0][j], 0.f), fmaxf(acc[1][j], 0.f),
                        fmaxf(acc[2][j], 0.f), fmaxf(acc[3][j], 0.f));
        *(float4*)&xsT[lk][base + 4] =
            make_float4(fmaxf(acc[4][j], 0.f), fmaxf(acc[5][j], 0.f),
                        fmaxf(acc[6][j], 0.f), fmaxf(acc[7][j], 0.f));
        int lk2 = 16 + txl * 4 + j;
        int base2 = ty8 ^ (((lk2 >> 2) & 3) << 3);
        *(float4*)&xsT[lk2][base2] =
            make_float4(fmaxf(acc[0][4 + j], 0.f), fmaxf(acc[1][4 + j], 0.f),
                        fmaxf(acc[2][4 + j], 0.f), fmaxf(acc[3][4 + j], 0.f));
        *(float4*)&xsT[lk2][base2 + 4] =
            make_float4(fmaxf(acc[4][4 + j], 0.f), fmaxf(acc[5][4 + j], 0.f),
                        fmaxf(acc[6][4 + j], 0.f), fmaxf(acc[7][4 + j], 0.f));
      }
    }
    for (int idx = threadIdx.x; idx < 32 * 32; idx += 256) {
      int c4 = (idx & 31) * 4, kk = idx >> 5;
      int gk = (kk < 16) ? (ch * 16 + kk) : (48 + ch * 16 + kk);
      *(float4*)&ws[kk][c4] = *(const float4*)(W2 + (size_t)gk * 128 + c4);
    }
    __syncthreads();
#pragma unroll 2
    for (int k = 0; k < 32; ++k) {
      int g8 = ((k >> 2) & 3) << 3;
      float4 a0 = *(const float4*)&xsT[k][ty8 ^ g8];
      float4 a1 = *(const float4*)&xsT[k][(ty8 ^ g8) + 4];
      float4 b0 = *(const float4*)&ws[k][tx * 4];
      float4 b1v = *(const float4*)&ws[k][64 + tx * 4];
      float av[8] = {a0.x, a0.y, a0.z, a0.w, a1.x, a1.y, a1.z, a1.w};
      float bv[8] = {b0.x, b0.y, b0.z, b0.w, b1v.x, b1v.y, b1v.z, b1v.w};
#pragma unroll
      for (int i = 0; i < 8; ++i)
#pragma unroll
        for (int j = 0; j < 8; ++j) acc3[i][j] += av[i] * bv[j];
    }
    __syncthreads();
  }
#pragma unroll
  for (int i = 0; i < 8; ++i) {
    int row = row0 + ty8 + i;
    if (row < N) {
      float* zr = Z + (size_t)row * 128;
      *(float4*)(zr + tx * 4) = make_float4(acc3[i][0], acc3[i][1], acc3[i][2], acc3[i][3]);
      *(float4*)(zr + 64 + tx * 4) = make_float4(acc3[i][4], acc3[i][5], acc3[i][6], acc3[i][7]);
    }
  }
}

// =================== CSR build: fused hist + SINGLE combined scan ===================
// hist = [histD(Nitem) | histS(Ncust)] contiguous. sum(histD)=E exactly, so the
// combined exclusive scan gives starts2 = scan - E for indices >= Nitem.

__global__ __launch_bounds__(256) void k_hist2(
    const int* __restrict__ src, const int* __restrict__ dst,
    int* __restrict__ histD, int* __restrict__ histS, int E) {
  int e = blockIdx.x * 256 + threadIdx.x;
  if (e >= E) return;
  atomicAdd(&histD[dst[e]], 1);
  atomicAdd(&histS[src[e]], 1);
}

#define SCAN_T 256
#define SCAN_V 4
#define SCAN_BLK 1024

__global__ __launch_bounds__(SCAN_T) void k_scan_local(
    const int* __restrict__ hist, int* __restrict__ starts,
    int* __restrict__ partials, int N) {
  __shared__ int sums[SCAN_T];
  int base = blockIdx.x * SCAN_BLK + threadIdx.x * SCAN_V;
  int v[SCAN_V];
  int s = 0;
#pragma unroll
  for (int i = 0; i < SCAN_V; ++i) { v[i] = (base + i < N) ? hist[base + i] : 0; s += v[i]; }
  sums[threadIdx.x] = s;
  __syncthreads();
  for (int off = 1; off < SCAN_T; off <<= 1) {
    int x = (threadIdx.x >= off) ? sums[threadIdx.x - off] : 0;
    __syncthreads();
    sums[threadIdx.x] += x;
    __syncthreads();
  }
  int run = (threadIdx.x > 0) ? sums[threadIdx.x - 1] : 0;
#pragma unroll
  for (int i = 0; i < SCAN_V; ++i) {
    if (base + i < N) starts[base + i] = run;
    run += v[i];
  }
  if (threadIdx.x == SCAN_T - 1) partials[blockIdx.x] = sums[SCAN_T - 1];
}

__global__ __launch_bounds__(SCAN_T) void k_scan_partials(int* partials, int nb) {
  __shared__ int s[SCAN_T];
  s[threadIdx.x] = (threadIdx.x < nb) ? partials[threadIdx.x] : 0;
  __syncthreads();
  for (int off = 1; off < SCAN_T; off <<= 1) {
    int x = (threadIdx.x >= off) ? s[threadIdx.x - off] : 0;
    __syncthreads();
    s[threadIdx.x] += x;
    __syncthreads();
  }
  if (threadIdx.x < nb) partials[threadIdx.x] = (threadIdx.x > 0) ? s[threadIdx.x - 1] : 0;
}

// combined: subtract E for indices >= Nsplit (second array's base offset)
__global__ __launch_bounds__(256) void k_scan_add(
    int* __restrict__ starts, const int* __restrict__ partials,
    int* __restrict__ cursor, int N, int Nsplit, int E) {
  int i = blockIdx.x * 256 + threadIdx.x;
  if (i >= N) return;
  int v = starts[i] + partials[i / SCAN_BLK];
  if (i >= Nsplit) v -= E;
  starts[i] = v;
  cursor[i] = v;
}

__global__ __launch_bounds__(256) void k_scatter2(
    const int* __restrict__ src, const int* __restrict__ dst,
    int* __restrict__ cur1, int* __restrict__ cur2,
    int2* __restrict__ ebuf1, int2* __restrict__ ebuf2, int E) {
  int e = blockIdx.x * 256 + threadIdx.x;
  if (e >= E) return;
  int s = src[e], d = dst[e];
  int p1 = atomicAdd(&cur1[d], 1);
  ebuf1[p1] = make_int2(s, e);
  int p2 = atomicAdd(&cur2[s], 1);
  ebuf2[p2] = make_int2(d, e);
}

// =================== fused GATv2 edge phase: 4-way ILP online softmax (R14-proven) ===================
template <int USE_EF>
__global__ __launch_bounds__(256) void k_gat(
    const float* __restrict__ xl, const float* __restrict__ xr,
    const int2* __restrict__ ebuf, const int* __restrict__ starts,
    const int* __restrict__ counts, const float* __restrict__ att,
    const float* __restrict__ eattr, const float* __restrict__ We,
    float* __restrict__ agg, int N) {
  int wid = (blockIdx.x * 256 + threadIdx.x) >> 6;
  if (wid >= N) return;
  int lane = threadIdx.x & 63;
  int g = lane >> 4;
  int t = lane & 15;
  int c = g * 32 + t * 2;
  float att0 = att[c], att1 = att[c + 1];
  float2 we0, we1, we2;
  if (USE_EF) {
    we0 = *(const float2*)(We + 0 * HC + c);
    we1 = *(const float2*)(We + 1 * HC + c);
    we2 = *(const float2*)(We + 2 * HC + c);
  }
  float2 xrv = *(const float2*)(xr + (size_t)wid * HC + c);
  int st = starts[wid], cnt = counts[wid];
  const float NEGINF = -3.402823466e38f;
  float m0 = NEGINF, d0 = 0.f, a00 = 0.f, a01 = 0.f;
  float m1 = NEGINF, d1 = 0.f, a10 = 0.f, a11 = 0.f;
  float m2 = NEGINF, d2 = 0.f, a20 = 0.f, a21 = 0.f;
  float m3 = NEGINF, d3 = 0.f, a30 = 0.f, a31 = 0.f;
  int i = 0;
  for (; i + 3 < cnt; i += 4) {
    int2 seA = ebuf[st + i];
    int2 seB = ebuf[st + i + 1];
    int2 seC = ebuf[st + i + 2];
    int2 seD = ebuf[st + i + 3];
    float2 xlA = *(const float2*)(xl + (size_t)seA.x * HC + c);
    float2 xlB = *(const float2*)(xl + (size_t)seB.x * HC + c);
    float2 xlC = *(const float2*)(xl + (size_t)seC.x * HC + c);
    float2 xlD = *(const float2*)(xl + (size_t)seD.x * HC + c);
    float xA0 = xlA.x + xrv.x, xA1 = xlA.y + xrv.y;
    float xB0 = xlB.x + xrv.x, xB1 = xlB.y + xrv.y;
    float xC0 = xlC.x + xrv.x, xC1 = xlC.y + xrv.y;
    float xD0 = xlD.x + xrv.x, xD1 = xlD.y + xrv.y;
    if (USE_EF) {
      const float* eaA = eattr + (size_t)seA.y * 3;
      const float* eaB = eattr + (size_t)seB.y * 3;
      const float* eaC = eattr + (size_t)seC.y * 3;
      const float* eaD = eattr + (size_t)seD.y * 3;
      float eA0 = eaA[0], eA1 = eaA[1], eA2 = eaA[2];
      float eB0 = eaB[0], eB1 = eaB[1], eB2 = eaB[2];
      float eC0 = eaC[0], eC1 = eaC[1], eC2 = eaC[2];
      float eD0 = eaD[0], eD1 = eaD[1], eD2 = eaD[2];
      xA0 += eA0 * we0.x + eA1 * we1.x + eA2 * we2.x;
      xA1 += eA0 * we0.y + eA1 * we1.y + eA2 * we2.y;
      xB0 += eB0 * we0.x + eB1 * we1.x + eB2 * we2.x;
      xB1 += eB0 * we0.y + eB1 * we1.y + eB2 * we2.y;
      xC0 += eC0 * we0.x + eC1 * we1.x + eC2 * we2.x;
      xC1 += eC0 * we0.y + eC1 * we1.y + eC2 * we2.y;
      xD0 += eD0 * we0.x + eD1 * we1.x + eD2 * we2.x;
      xD1 += eD0 * we0.y + eD1 * we1.y + eD2 * we2.y;
    }
    xA0 = (xA0 > 0.f) ? xA0 : 0.2f * xA0;
    xA1 = (xA1 > 0.f) ? xA1 : 0.2f * xA1;
    xB0 = (xB0 > 0.f) ? xB0 : 0.2f * xB0;
    xB1 = (xB1 > 0.f) ? xB1 : 0.2f * xB1;
    xC0 = (xC0 > 0.f) ? xC0 : 0.2f * xC0;
    xC1 = (xC1 > 0.f) ? xC1 : 0.2f * xC1;
    xD0 = (xD0 > 0.f) ? xD0 : 0.2f * xD0;
    xD1 = (xD1 > 0.f) ? xD1 : 0.2f * xD1;
    float pA = xA0 * att0 + xA1 * att1;
    float pB = xB0 * att0 + xB1 * att1;
    float pC = xC0 * att0 + xC1 * att1;
    float pD = xD0 * att0 + xD1 * att1;
    pA += __shfl_xor(pA, 1, 16);
    pB += __shfl_xor(pB, 1, 16);
    pC += __shfl_xor(pC, 1, 16);
    pD += __shfl_xor(pD, 1, 16);
    pA += __shfl_xor(pA, 2, 16);
    pB += __shfl_xor(pB, 2, 16);
    pC += __shfl_xor(pC, 2, 16);
    pD += __shfl_xor(pD, 2, 16);
    pA += __shfl_xor(pA, 4, 16);
    pB += __shfl_xor(pB, 4, 16);
    pC += __shfl_xor(pC, 4, 16);
    pD += __shfl_xor(pD, 4, 16);
    pA += __shfl_xor(pA, 8, 16);
    pB += __shfl_xor(pB, 8, 16);
    pC += __shfl_xor(pC, 8, 16);
    pD += __shfl_xor(pD, 8, 16);
    float nmA = fmaxf(m0, pA), nmB = fmaxf(m1, pB);
    float nmC = fmaxf(m2, pC), nmD = fmaxf(m3, pD);
    float sA = __expf(m0 - nmA), wA = __expf(pA - nmA);
    float sB = __expf(m1 - nmB), wB = __expf(pB - nmB);
    float sC = __expf(m2 - nmC), wC = __expf(pC - nmC);
    float sD = __expf(m3 - nmD), wD = __expf(pD - nmD);
    d0 = d0 * sA + wA; a00 = a00 * sA + wA * xlA.x; a01 = a01 * sA + wA * xlA.y; m0 = nmA;
    d1 = d1 * sB + wB; a10 = a10 * sB + wB * xlB.x; a11 = a11 * sB + wB * xlB.y; m1 = nmB;
    d2 = d2 * sC + wC; a20 = a20 * sC + wC * xlC.x; a21 = a21 * sC + wC * xlC.y; m2 = nmC;
    d3 = d3 * sD + wD; a30 = a30 * sD + wD * xlD.x; a31 = a31 * sD + wD * xlD.y; m3 = nmD;
  }
  for (; i < cnt; ++i) {
    int2 se = ebuf[st + i];
    float2 xlv = *(const float2*)(xl + (size_t)se.x * HC + c);
    float x0 = xlv.x + xrv.x, x1 = xlv.y + xrv.y;
    if (USE_EF) {
      const float* ea = eattr + (size_t)se.y * 3;
      float e0 = ea[0], e1 = ea[1], e2 = ea[2];
      x0 += e0 * we0.x + e1 * we1.x + e2 * we2.x;
      x1 += e0 * we0.y + e1 * we1.y + e2 * we2.y;
    }
    x0 = (x0 > 0.f) ? x0 : 0.2f * x0;
    x1 = (x1 > 0.f) ? x1 : 0.2f * x1;
    float p = x0 * att0 + x1 * att1;
    p += __shfl_xor(p, 1, 16);
    p += __shfl_xor(p, 2, 16);
    p += __shfl_xor(p, 4, 16);
    p += __shfl_xor(p, 8, 16);
    float nm = fmaxf(m0, p);
    float s = __expf(m0 - nm), w = __expf(p - nm);
    d0 = d0 * s + w; a00 = a00 * s + w * xlv.x; a01 = a01 * s + w * xlv.y; m0 = nm;
  }
  float M = fmaxf(fmaxf(m0, m1), fmaxf(m2, m3));
  float s0 = (m0 > NEGINF) ? __expf(m0 - M) : 0.f;
  float s1 = (m1 > NEGINF) ? __expf(m1 - M) : 0.f;
  float s2 = (m2 > NEGINF) ? __expf(m2 - M) : 0.f;
  float s3 = (m3 > NEGINF) ? __expf(m3 - M) : 0.f;
  float dsum = d0 * s0 + d1 * s1 + d2 * s2 + d3 * s3;
  float a0 = a00 * s0 + a10 * s1 + a20 * s2 + a30 * s3;
  float a1 = a01 * s0 + a11 * s1 + a21 * s2 + a31 * s3;
  float inv = (dsum > 0.f) ? 1.f / dsum : 0.f;
  *(float2*)(agg + (size_t)wid * HC + c) = make_float2(a0 * inv, a1 * inv);
}

static inline int imin(int a, int b) { return a < b ? a : b; }

extern "C" void kernel_launch(void* const* d_in, const int* in_sizes, int n_in,
                              void* d_out, int out_size, void* d_ws, size_t ws_size,
                              hipStream_t stream) {
  const float* customer_x = (const float*)d_in[0];
  const float* fund_x     = (const float*)d_in[1];
  const int*   edge_src   = (const int*)d_in[2];
  const int*   edge_dst   = (const int*)d_in[3];
  const float* edge_attr  = (const float*)d_in[4];
  const float* user_W = (const float*)d_in[5];
  const float* user_b = (const float*)d_in[6];
  const float* item_W = (const float*)d_in[7];
  const float* item_b = (const float*)d_in[8];
  const float* c1_Wl = (const float*)d_in[9];
  const float* c1_bl = (const float*)d_in[10];
  const float* c1_Wr = (const float*)d_in[11];
  const float* c1_br = (const float*)d_in[12];
  const float* c1_att = (const float*)d_in[13];
  const float* c1_We  = (const float*)d_in[14];
  const float* c1_bias = (const float*)d_in[15];
  const float* c2_Wl = (const float*)d_in[16];
  const float* c2_bl = (const float*)d_in[17];
  const float* c2_Wr = (const float*)d_in[18];
  const float* c2_br = (const float*)d_in[19];
  const float* c2_att = (const float*)d_in[20];
  const float* c2_bias = (const float*)d_in[21];
  const float* proj_W1 = (const float*)d_in[22];
  const float* proj_b1 = (const float*)d_in[23];
  const float* proj_W2 = (const float*)d_in[24];
  const float* proj_b2 = (const float*)d_in[25];
  const float* cls_W1 = (const float*)d_in[26];
  const float* cls_b1 = (const float*)d_in[27];
  const float* cls_W2 = (const float*)d_in[28];
  const float* cls_b2 = (const float*)d_in[29];

  const int Ncust = in_sizes[0] / 101;
  const int Nitem = in_sizes[1];
  const int E     = in_sizes[2];
  const int NT    = Nitem + Ncust;   // combined CSR domain

  // -------- workspace layout (~141 MiB) --------
  float* w = (float*)d_ws;
  float* user_x  = w; w += (size_t)Ncust * 32;
  float* item_x0 = w; w += (size_t)Nitem * 32;
  float* bufC    = w; w += (size_t)Ncust * HC;   // xl1 -> (conv2 xl2 in first Nitem rows)
  float* bufD    = w; w += (size_t)Nitem * HC;   // xr1 -> agg1 (in-place)
  float* bufE    = w; w += (size_t)Ncust * HC;   // xr2 -> agg2 (in-place)
  int* hist    = (int*)w; w += NT;               // [histD(Nitem) | histS(Ncust)]
  int* starts  = (int*)w; w += NT;               // combined exclusive scans
  int* cursor  = (int*)w; w += NT;
  int* partials = (int*)w; w += 512;
  int2* ebuf1 = (int2*)w; w += (size_t)E * 2;
  int2* ebuf2 = (int2*)w; w += (size_t)E * 2;
  if ((size_t)((char*)w - (char*)d_ws) > ws_size) return;

  int* hist1 = hist;            int* hist2 = hist + Nitem;
  int* starts1 = starts;        int* starts2 = starts + Nitem;
  int* cursor1 = cursor;        int* cursor2 = cursor + Nitem;

  float* out_scores = (float*)d_out;
  float* out_z      = out_scores + Ncust;

  const int egrid = (E + 255) / 256;
  const int nbT = (NT + SCAN_BLK - 1) / SCAN_BLK;   // <= 256 for N <= 256K
  const int nt1 = (Ncust + 127) / 128;
  const int nt2 = (Nitem + 127) / 128;

  // -------- CSR build: 1 memset + 5 kernels (was 9) --------
  hipMemsetAsync(hist, 0, (size_t)NT * 4, stream);
  k_hist2<<<egrid, 256, 0, stream>>>(edge_src, edge_dst, hist1, hist2, E);
  k_scan_local<<<nbT, SCAN_T, 0, stream>>>(hist, starts, partials, NT);
  k_scan_partials<<<1, SCAN_T, 0, stream>>>(partials, nbT);
  k_scan_add<<<(NT + 255) / 256, 256, 0, stream>>>(starts, partials, cursor, NT, Nitem, E);
  k_scatter2<<<egrid, 256, 0, stream>>>(edge_src, edge_dst, cursor1, cursor2, ebuf1, ebuf2, E);

  // -------- node projections --------
  k_proj101<<<(Ncust + 63) / 64, 256, 0, stream>>>(customer_x, user_W, user_b, user_x, Ncust);
  k_item_proj<<<(Nitem * 32 + 255) / 256, 256, 0, stream>>>(fund_x, item_W, item_b, item_x0, Nitem);

  // -------- conv linear parts from user_x (xl1 + xr2 in one pass) --------
  k_dual32<<<nt1, 256, 0, stream>>>(user_x, c1_Wl, c1_bl, c2_Wr, c2_br, bufC, bufE, Ncust);
  k_tile<32, 0, 0><<<nt2, 256, 0, stream>>>(item_x0, nullptr, c1_Wr, c1_br, bufD, Nitem);

  // -------- conv1 edge phase (customer -> fund), agg1 in-place into bufD --------
  k_gat<1><<<(Nitem + 3) / 4, 256, 0, stream>>>(bufC, bufD, ebuf1, starts1, hist1,
                                                c1_att, edge_attr, c1_We, bufD, Nitem);

  // -------- conv2: xl2 then edge phase (fund -> customer) in-place bufE --------
  k_tile<128, 1, 0><<<nt2, 256, 0, stream>>>(bufD, c1_bias, c2_Wl, c2_bl, bufC, Nitem);
  k_gat<0><<<(Ncust + 3) / 4, 256, 0, stream>>>(bufC, bufE, ebuf2, starts2, hist2,
                                                c2_att, nullptr, nullptr, bufE, Ncust);

  // -------- fused head: proj1 + cls + proj2 --------
  k_head_fused<<<nt1, 256, 0, stream>>>(bufE, c2_bias, proj_W1, proj_b1, proj_W2, proj_b2,
                                        cls_W1, cls_b1, cls_W2, cls_b2,
                                        out_z, out_scores, Ncust);
}